// Round 1
// baseline (3245.173 us; speedup 1.0000x reference)
//
#include <hip/hip_runtime.h>
#include <hip/hip_bf16.h>

namespace {

constexpr int T_SEQ = 512;
constexpr int B_SZ  = 1024;
constexpr int H_DIM = 128;
constexpr int G3    = 384;     // 3*H
constexpr int RPB   = 4;       // batch rows per block
constexpr int NTHR  = 768;     // 2 * G3 threads (12 waves)

__device__ __forceinline__ float fast_sigmoid(float x) {
  x = fminf(fmaxf(x, -30.f), 30.f);
  return 1.f / (1.f + __expf(-x));
}
__device__ __forceinline__ float fast_tanh(float x) {
  x = fminf(fmaxf(x, -15.f), 15.f);
  const float e = __expf(2.f * x);
  return (e - 1.f) / (e + 1.f);
}

__device__ __forceinline__ float ld_in(const float* p) { return *p; }
__device__ __forceinline__ float ld_in(const __hip_bfloat16* p) { return __bfloat162float(*p); }
__device__ __forceinline__ void st_out(float* p, float v) { *p = v; }
__device__ __forceinline__ void st_out(__hip_bfloat16* p, float v) { *p = __float2bfloat16(v); }

// One GRU layer. Each block owns RPB batch rows for the entire sequence.
// Thread (g, kh) owns gate-row g and k-half kh of both weight matrices,
// held in registers for all 512 steps. h lives in LDS (broadcast reads).
template <int INDIM, typename InT, typename OutT, bool STORE_ALL>
__global__ __launch_bounds__(NTHR, 3)
void gru_layer_kernel(const InT*  __restrict__ in,     // (B, T, INDIM)
                      const float* __restrict__ w_ih,  // (3H, INDIM)
                      const float* __restrict__ w_hh,  // (3H, H)
                      const float* __restrict__ b_ih,  // (3H)
                      const float* __restrict__ b_hh,  // (3H)
                      OutT* __restrict__ out)          // STORE_ALL ? (B,T,H) : (B,H)
{
  constexpr int KIH = INDIM / 2;   // per-thread w_ih slice
  constexpr int KHH = H_DIM / 2;   // per-thread w_hh slice = 64

  const int tid = threadIdx.x;
  const int kh  = (tid >= G3) ? 1 : 0;
  const int g   = tid - kh * G3;
  const int r0  = blockIdx.x * RPB;

  __shared__ __align__(16) float h_s[RPB][H_DIM];
  __shared__ __align__(16) float in_s[RPB][INDIM];
  __shared__ __align__(16) float pxg[2][RPB][G3];
  __shared__ __align__(16) float phg[2][RPB][G3];

  for (int i = tid; i < RPB * H_DIM; i += NTHR) (&h_s[0][0])[i] = 0.f;

  // ---- weights -> registers (once) ----
  float wih[KIH];
  {
    const float4* src = reinterpret_cast<const float4*>(w_ih + (size_t)g * INDIM + kh * KIH);
    #pragma unroll
    for (int k4 = 0; k4 < KIH / 4; ++k4) {
      const float4 v = src[k4];
      wih[4*k4+0] = v.x; wih[4*k4+1] = v.y; wih[4*k4+2] = v.z; wih[4*k4+3] = v.w;
    }
  }
  float whh[KHH];
  {
    const float4* src = reinterpret_cast<const float4*>(w_hh + (size_t)g * H_DIM + kh * KHH);
    #pragma unroll
    for (int k4 = 0; k4 < KHH / 4; ++k4) {
      const float4 v = src[k4];
      whh[4*k4+0] = v.x; whh[4*k4+1] = v.y; whh[4*k4+2] = v.z; whh[4*k4+3] = v.w;
    }
  }
  const float bi = (kh == 0) ? b_ih[g] : 0.f;
  const float bh = (kh == 0) ? b_hh[g] : 0.f;

  // ---- stage t=0 input ----
  const int sr = tid / INDIM;              // INDIM is pow2
  const int sc = tid - sr * INDIM;
  const bool do_stage = (tid < RPB * INDIM);
  float stg = 0.f;
  if (do_stage) stg = ld_in(in + (size_t)(r0 + sr) * T_SEQ * INDIM + sc);

  __syncthreads();   // h_s init visible

  #pragma unroll 1
  for (int t = 0; t < T_SEQ; ++t) {
    if (do_stage) in_s[sr][sc] = stg;
    __syncthreads();                       // in_s + h_s ready

    // prefetch next timestep's input (latency hidden under compute)
    if (do_stage && (t + 1 < T_SEQ))
      stg = ld_in(in + (size_t)(r0 + sr) * T_SEQ * INDIM + (size_t)(t + 1) * INDIM + sc);

    // partial dot products: xg and hg for gate g, k-half kh, all 4 rows
    #pragma unroll
    for (int r = 0; r < RPB; ++r) {
      float ax = bi;
      float ah = bh;
      const float4* xi = reinterpret_cast<const float4*>(&in_s[r][kh * KIH]);
      #pragma unroll
      for (int k4 = 0; k4 < KIH / 4; ++k4) {
        const float4 v = xi[k4];
        ax += wih[4*k4+0] * v.x; ax += wih[4*k4+1] * v.y;
        ax += wih[4*k4+2] * v.z; ax += wih[4*k4+3] * v.w;
      }
      const float4* hi = reinterpret_cast<const float4*>(&h_s[r][kh * KHH]);
      #pragma unroll
      for (int k4 = 0; k4 < KHH / 4; ++k4) {
        const float4 v = hi[k4];
        ah += whh[4*k4+0] * v.x; ah += whh[4*k4+1] * v.y;
        ah += whh[4*k4+2] * v.z; ah += whh[4*k4+3] * v.w;
      }
      pxg[kh][r][g] = ax;
      phg[kh][r][g] = ah;
    }
    __syncthreads();                       // partials ready

    // gate combine: 512 tasks (r, j), threads 0..511
    if (tid < RPB * H_DIM) {
      const int r = tid >> 7;
      const int j = tid & (H_DIM - 1);
      const float xr = pxg[0][r][j]             + pxg[1][r][j];
      const float xz = pxg[0][r][H_DIM + j]     + pxg[1][r][H_DIM + j];
      const float xn = pxg[0][r][2 * H_DIM + j] + pxg[1][r][2 * H_DIM + j];
      const float hr = phg[0][r][j]             + phg[1][r][j];
      const float hz = phg[0][r][H_DIM + j]     + phg[1][r][H_DIM + j];
      const float hn = phg[0][r][2 * H_DIM + j] + phg[1][r][2 * H_DIM + j];
      const float rr = fast_sigmoid(xr + hr);
      const float zz = fast_sigmoid(xz + hz);
      const float nn = fast_tanh(xn + rr * hn);
      const float hv = (1.f - zz) * nn + zz * h_s[r][j];
      h_s[r][j] = hv;
      if (STORE_ALL) {
        st_out(out + (size_t)(r0 + r) * T_SEQ * H_DIM + (size_t)t * H_DIM + j, hv);
      } else if (t == T_SEQ - 1) {
        st_out(out + (size_t)(r0 + r) * H_DIM + j, hv);
      }
    }
    // next-iter top writes in_s (consumed before 2nd barrier) and the 1st
    // barrier of the next iteration orders the h_s update -> 2 barriers/step.
  }
}

// FC head: out = fc2( BN( relu( fc1(h2_last) ) ) ); one row per block.
__global__ __launch_bounds__(64)
void head_kernel(const float* __restrict__ h2,     // (B, H)
                 const float* __restrict__ fc1_w,  // (64, 128)
                 const float* __restrict__ fc1_b,  // (64)
                 const float* __restrict__ fc2_w,  // (2, 64)
                 const float* __restrict__ fc2_b,  // (2)
                 const float* __restrict__ gamma,
                 const float* __restrict__ beta,
                 const float* __restrict__ mean,
                 const float* __restrict__ var,
                 float* __restrict__ out)          // (B, 2)
{
  const int row = blockIdx.x;
  const int j   = threadIdx.x;   // 0..63
  __shared__ __align__(16) float hrow[H_DIM];
  __shared__ __align__(16) float act[64];

  hrow[j]      = h2[(size_t)row * H_DIM + j];
  hrow[64 + j] = h2[(size_t)row * H_DIM + 64 + j];
  __syncthreads();

  float s = fc1_b[j];
  const float4* wr = reinterpret_cast<const float4*>(fc1_w + (size_t)j * H_DIM);
  #pragma unroll
  for (int k4 = 0; k4 < H_DIM / 4; ++k4) {
    const float4 w = wr[k4];
    const float4 h = reinterpret_cast<const float4*>(hrow)[k4];
    s += w.x * h.x + w.y * h.y + w.z * h.z + w.w * h.w;
  }
  s = fmaxf(s, 0.f);
  s = (s - mean[j]) * rsqrtf(var[j] + 1e-5f) * gamma[j] + beta[j];
  act[j] = s;
  __syncthreads();

  if (j < 2) {
    float o = fc2_b[j];
    #pragma unroll
    for (int k = 0; k < 64; ++k) o += fc2_w[(size_t)j * 64 + k] * act[k];
    out[(size_t)row * 2 + j] = o;
  }
}

} // namespace

extern "C" void kernel_launch(void* const* d_in, const int* in_sizes, int n_in,
                              void* d_out, int out_size, void* d_ws, size_t ws_size,
                              hipStream_t stream) {
  const float* x     = (const float*)d_in[0];
  const float* w_ih0 = (const float*)d_in[1];
  const float* w_hh0 = (const float*)d_in[2];
  const float* b_ih0 = (const float*)d_in[3];
  const float* b_hh0 = (const float*)d_in[4];
  const float* w_ih1 = (const float*)d_in[5];
  const float* w_hh1 = (const float*)d_in[6];
  const float* b_ih1 = (const float*)d_in[7];
  const float* b_hh1 = (const float*)d_in[8];
  const float* fc1_w = (const float*)d_in[9];
  const float* fc1_b = (const float*)d_in[10];
  const float* fc2_w = (const float*)d_in[11];
  const float* fc2_b = (const float*)d_in[12];
  const float* gamma = (const float*)d_in[13];
  const float* beta  = (const float*)d_in[14];
  const float* mean  = (const float*)d_in[15];
  const float* var   = (const float*)d_in[16];
  float* out = (float*)d_out;

  char* ws = (char*)d_ws;
  const size_t h2_bytes  = (size_t)B_SZ * H_DIM * sizeof(float);
  float* h2_last = (float*)ws;
  char*  h1_raw  = ws + h2_bytes;
  const size_t h1_elems = (size_t)B_SZ * T_SEQ * H_DIM;

  const dim3 gridG(B_SZ / RPB);
  const dim3 blockG(NTHR);

  if (ws_size >= h2_bytes + h1_elems * sizeof(float)) {
    float* h1 = (float*)h1_raw;
    gru_layer_kernel<64, float, float, true>
        <<<gridG, blockG, 0, stream>>>(x, w_ih0, w_hh0, b_ih0, b_hh0, h1);
    gru_layer_kernel<128, float, float, false>
        <<<gridG, blockG, 0, stream>>>(h1, w_ih1, w_hh1, b_ih1, b_hh1, h2_last);
  } else if (ws_size >= h2_bytes + h1_elems * sizeof(__hip_bfloat16)) {
    __hip_bfloat16* h1 = (__hip_bfloat16*)h1_raw;
    gru_layer_kernel<64, float, __hip_bfloat16, true>
        <<<gridG, blockG, 0, stream>>>(x, w_ih0, w_hh0, b_ih0, b_hh0, h1);
    gru_layer_kernel<128, __hip_bfloat16, float, false>
        <<<gridG, blockG, 0, stream>>>(h1, w_ih1, w_hh1, b_ih1, b_hh1, h2_last);
  } else {
    return;  // workspace too small for any valid plan — fail visibly
  }

  head_kernel<<<dim3(B_SZ), dim3(64), 0, stream>>>(
      h2_last, fc1_w, fc1_b, fc2_w, fc2_b, gamma, beta, mean, var, out);
}